// Round 1
// baseline (129.942 us; speedup 1.0000x reference)
//
#include <hip/hip_runtime.h>

// BlurModel: 100x100 box filter (VALID) * 1e-4 over (8,3,1024,1024) f32,
// then where(v > 0.129, 1.0, v).  N*C = 24 images of 1024x1024 -> 925x925.
//
// Separable sliding-window implementation:
//   V_i[j]  = sum_{di<100} x[i+di][j]           (vertical running column sum, LDS)
//   P       = exclusive prefix of V_i            (block scan, shfl_up + LDS)
//   out[i][j] = 1e-4 * (P[j+100] - P[j])         (horizontal window via prefix diff)

#define KS      100
#define KVALF   1e-4f
#define THRESHF 0.129f
#define HH      1024
#define WW      1024
#define OHH     925
#define OWW     925
#define TJ      256           // output columns per strip
#define NSTRIP  4             // ceil(925/256)
#define NCHUNK  8             // row chunks per image
#define CH      116           // ceil(925/8)
#define NIMG    24            // 8*3

__global__ __launch_bounds__(256) void blur925(const float* __restrict__ x,
                                               float* __restrict__ out) {
    // padded to 512 slots so the float2 scan reads need no bounds checks
    __shared__ __align__(16) float cs[512];   // column sums V_i (slots >= seg stay 0)
    __shared__ __align__(16) float P[512];    // exclusive prefix of cs
    __shared__ float wtot[4];                 // per-wave scan totals

    const int tid  = threadIdx.x;
    const int lane = tid & 63;
    const int wid  = tid >> 6;

    const int strip = blockIdx.x;
    const int chunk = blockIdx.y;
    const int img   = blockIdx.z;

    const int j0     = strip * TJ;
    const int jcount = min(TJ, OWW - j0);     // 256 or 157 (last strip)
    const int seg    = jcount + (KS - 1);     // 355 or 256 input columns needed

    const int r0 = chunk * CH;
    const int r1 = min(OHH, r0 + CH);

    const float* __restrict__ xi = x + (size_t)img * HH * WW + j0;
    float* __restrict__ oi       = out + (size_t)img * OHH * OWW;

    const int  m0   = tid;          // always < seg (seg >= 256)
    const int  m1   = tid + 256;
    const bool has1 = (m1 < seg);

    // ---- init: V_{r0}[j] = sum of rows r0..r0+99 (coalesced row reads) ----
    float a0 = 0.f, a1 = 0.f;
    for (int r = r0; r < r0 + KS; ++r) {
        const float* row = xi + (size_t)r * WW;
        a0 += row[m0];
        if (has1) a1 += row[m1];
    }
    cs[m0] = a0;
    cs[m1] = has1 ? a1 : 0.f;   // zero-pads slots seg..511

    for (int i = r0; i < r1; ++i) {
        __syncthreads();  // B1: cs updates (init or prev iter) visible

        // prefetch next-row update operands early; consumed after the scan
        const bool upd = (i + 1 < r1);
        float n0 = 0.f, n1 = 0.f, o0 = 0.f, o1 = 0.f;
        if (upd) {
            const float* rn = xi + (size_t)(i + KS) * WW;  // row entering window
            const float* ro = xi + (size_t)i * WW;         // row leaving window
            n0 = rn[m0]; o0 = ro[m0];
            if (has1) { n1 = rn[m1]; o1 = ro[m1]; }
        }

        // ---- block exclusive scan over 512 slots, 2 slots/thread ----
        const float2 e  = ((const float2*)cs)[tid];  // conflict-free b64 read
        const float  s  = e.x + e.y;
        float inc = s;
#pragma unroll
        for (int d = 1; d < 64; d <<= 1) {
            float up = __shfl_up(inc, d, 64);
            if (lane >= d) inc += up;
        }
        if (lane == 63) wtot[wid] = inc;
        __syncthreads();  // B2
        float woff = 0.f;
#pragma unroll
        for (int w = 0; w < 3; ++w)
            if (w < wid) woff += wtot[w];
        const float excl = woff + (inc - s);
        ((float2*)P)[tid] = make_float2(excl, excl + e.x);  // conflict-free b64 write
        __syncthreads();  // B3

        // ---- output: horizontal window = prefix difference, + threshold ----
        if (tid < jcount) {
            const float v = KVALF * (P[tid + KS] - P[tid]);
            oi[(size_t)i * OWW + (j0 + tid)] = (v > THRESHF) ? 1.0f : v;
        }

        // ---- slide the vertical window (cs reads for the scan were pre-B2) ----
        if (upd) {
            cs[m0] += n0 - o0;
            if (has1) cs[m1] += n1 - o1;
        }
    }
}

extern "C" void kernel_launch(void* const* d_in, const int* in_sizes, int n_in,
                              void* d_out, int out_size, void* d_ws, size_t ws_size,
                              hipStream_t stream) {
    const float* x = (const float*)d_in[0];
    float* out     = (float*)d_out;
    dim3 grid(NSTRIP, NCHUNK, NIMG);
    blur925<<<grid, dim3(256), 0, stream>>>(x, out);
}